// Round 1
// baseline (926.222 us; speedup 1.0000x reference)
//
#include <hip/hip_runtime.h>
#include <stdint.h>

#define N_POINTS   1048576
#define N_LEVELS   16
#define HASHMAP    524288u        // 1<<19
#define HASH_MASK  (HASHMAP - 1u)
#define PI1        2654435761u
#define PI2        805459861u

typedef float v2  __attribute__((ext_vector_type(2)));   // one table entry (8B)
typedef float v4f __attribute__((ext_vector_type(4)));   // aligned entry PAIR (16B)

// int(16 * (32^(1/15))^i) for i in 0..15, replicated exactly from the reference
__constant__ float c_res[16] = {16.f,20.f,25.f,32.f,40.f,50.f,64.f,80.f,
                                101.f,128.f,161.f,203.f,256.f,322.f,406.f,512.f};
// phase order: alternate coarse/fine so adjacent-in-time levels' tables fit L2
__constant__ int c_perm[16] = {0,15,1,14,2,13,3,12,4,11,5,10,6,9,7,8};

// L2-request-minimized gather: x-prime is 1, so for even ix the two x-corners
// are adjacent table entries -> one aligned 16B load serves both. Odd-ix lanes
// take a divergent branch for the 4 extra 8B loads (exec-masked lanes issue no
// L2 requests). Avg 6 requests/point/level instead of 8.
__device__ __forceinline__ v2 enc_point_level(const float* __restrict__ x,
                                              const float* __restrict__ tables,
                                              int p, int level, float res) {
    float x0 = x[3*p+0], x1 = x[3*p+1], x2 = x[3*p+2];
    float sx = x0*res, sy = x1*res, sz = x2*res;
    int ix = (int)sx, iy = (int)sy, iz = (int)sz;   // trunc == floor for x>=0
    float fx = sx - (float)ix, fy = sy - (float)iy, fz = sz - (float)iz;
    uint32_t ux  = (uint32_t)ix;
    uint32_t hy0 = (uint32_t)iy * PI1, hy1 = hy0 + PI1;
    uint32_t hz0 = (uint32_t)iz * PI2, hz1 = hz0 + PI2;
    uint32_t e0 = hy0 ^ hz0, e1 = hy1 ^ hz0, e2 = hy0 ^ hz1, e3 = hy1 ^ hz1;

    const v2*  __restrict__ tab  = (const v2*)tables + (size_t)level * HASHMAP;
    const v4f* __restrict__ tab4 = (const v4f*)tab;

    uint32_t iA0 = (ux ^ e0) & HASH_MASK;   // x=0 corner indices
    uint32_t iA1 = (ux ^ e1) & HASH_MASK;
    uint32_t iA2 = (ux ^ e2) & HASH_MASK;
    uint32_t iA3 = (ux ^ e3) & HASH_MASK;

    // 4x 16B paired loads: entries {iA & ~1, iA | 1}, issued back-to-back
    v4f q0 = tab4[iA0 >> 1];
    v4f q1 = tab4[iA1 >> 1];
    v4f q2 = tab4[iA2 >> 1];
    v4f q3 = tab4[iA3 >> 1];

    // x=0 corner = half (iA&1) of the pair
    v2 a0 = (iA0 & 1) ? (v2){q0.z,q0.w} : (v2){q0.x,q0.y};
    v2 a1 = (iA1 & 1) ? (v2){q1.z,q1.w} : (v2){q1.x,q1.y};
    v2 a2 = (iA2 & 1) ? (v2){q2.z,q2.w} : (v2){q2.x,q2.y};
    v2 a3 = (iA3 & 1) ? (v2){q3.z,q3.w} : (v2){q3.x,q3.y};

    // even ix: x=1 corner is entry iA^1 = the OTHER half (free).
    v2 b0 = (iA0 & 1) ? (v2){q0.x,q0.y} : (v2){q0.z,q0.w};
    v2 b1 = (iA1 & 1) ? (v2){q1.x,q1.y} : (v2){q1.z,q1.w};
    v2 b2 = (iA2 & 1) ? (v2){q2.x,q2.y} : (v2){q2.z,q2.w};
    v2 b3 = (iA3 & 1) ? (v2){q3.x,q3.y} : (v2){q3.z,q3.w};

    // odd ix: (ix+1)^e carries past bit0 -> separate 8B loads, odd lanes only.
    // Loads can't be speculated by the compiler -> stays a real exec-masked
    // branch; inactive lanes generate no L2 traffic.
    if (ix & 1) {
        uint32_t vx1 = ux + 1u;
        b0 = tab[(vx1 ^ e0) & HASH_MASK];
        b1 = tab[(vx1 ^ e1) & HASH_MASK];
        b2 = tab[(vx1 ^ e2) & HASH_MASK];
        b3 = tab[(vx1 ^ e3) & HASH_MASK];
    }

    float wx1 = fx, wx0 = 1.f - fx;
    float wy1 = fy, wy0 = 1.f - fy;
    float wz1 = fz, wz0 = 1.f - fz;
    float w00 = wy0*wz0, w10 = wy1*wz0, w01 = wy0*wz1, w11 = wy1*wz1;
    float c0 = wx0*w00, c1 = wx1*w00, c2 = wx0*w10, c3 = wx1*w10;
    float c4 = wx0*w01, c5 = wx1*w01, c6 = wx0*w11, c7 = wx1*w11;
    v2 r;
    r.x = c0*a0.x + c1*b0.x + c2*a1.x + c3*b1.x + c4*a2.x + c5*b2.x + c6*a3.x + c7*b3.x;
    r.y = c0*a0.y + c1*b0.y + c2*a1.y + c3*b1.y + c4*a2.y + c5*b2.y + c6*a3.y + c7*b3.y;
    return r;
}

// Pass 1 (phased): blockIdx level-major -> whole device sweeps one level at a
// time -> that level's 4 MB table is per-XCD-L2-resident. Writes level-major
// workspace coalesced (v2/lane), nontemporal so it doesn't evict table lines.
__global__ __launch_bounds__(256) void hash_enc_phase(const float* __restrict__ x,
                                                      const float* __restrict__ tables,
                                                      v2* __restrict__ ws) {
    int level = c_perm[blockIdx.x >> 12];           // 4096 blocks per level
    int p = ((blockIdx.x & 4095) << 8) | threadIdx.x;
    v2 r = enc_point_level(x, tables, p, level, c_res[level]);
    __builtin_nontemporal_store(r, ws + (size_t)level * N_POINTS + p);
}

// Pass 2: (L, N, 2) -> (N, L*2), register-only. Each thread owns one point:
// 16 coalesced 8B stream loads, then the 128B output row as 8 per-lane
// dwordx4 NT stores (every 64B line fully written by one wave -> no write
// amplification; no LDS, no barrier, full MLP).
__global__ __launch_bounds__(256) void untranspose(const v2* __restrict__ ws,
                                                   v4f* __restrict__ out) {
    int p = blockIdx.x * 256 + threadIdx.x;
    v2 r[16];
    #pragma unroll
    for (int l = 0; l < 16; ++l)
        r[l] = ws[(size_t)l * N_POINTS + p];
    #pragma unroll
    for (int k = 0; k < 8; ++k) {
        v4f v = {r[2*k].x, r[2*k].y, r[2*k+1].x, r[2*k+1].y};
        __builtin_nontemporal_store(v, out + (size_t)p * 8 + k);
    }
}

// Fallback if ws too small: fused, thread = (point, level) interleaved so the
// v2 output store is perfectly coalesced. Gathers mix all 16 levels (L2
// thrash) — slower, but correct with zero workspace.
__global__ __launch_bounds__(256) void hash_enc_fused(const float* __restrict__ x,
                                                      const float* __restrict__ tables,
                                                      v2* __restrict__ out) {
    int tid = blockIdx.x * 256 + threadIdx.x;       // 16M threads
    int level = tid & 15;
    int p = tid >> 4;
    v2 r = enc_point_level(x, tables, p, level, c_res[level]);
    out[tid] = r;
}

extern "C" void kernel_launch(void* const* d_in, const int* in_sizes, int n_in,
                              void* d_out, int out_size, void* d_ws, size_t ws_size,
                              hipStream_t stream) {
    const float* x      = (const float*)d_in[0];
    const float* tables = (const float*)d_in[1];
    size_t need = (size_t)N_LEVELS * N_POINTS * sizeof(v2);   // 128 MB
    if (ws_size >= need) {
        hash_enc_phase<<<dim3(65536), dim3(256), 0, stream>>>(x, tables, (v2*)d_ws);
        untranspose<<<dim3(4096), dim3(256), 0, stream>>>((const v2*)d_ws, (v4f*)d_out);
    } else {
        hash_enc_fused<<<dim3(65536), dim3(256), 0, stream>>>(x, tables, (v2*)d_out);
    }
}

// Round 2
// 802.058 us; speedup vs baseline: 1.1548x; 1.1548x over previous
//
#include <hip/hip_runtime.h>
#include <stdint.h>

#define N_POINTS   1048576
#define N_LEVELS   16
#define HASHMAP    524288u        // 1<<19
#define HASH_MASK  (HASHMAP - 1u)
#define PI1        2654435761u
#define PI2        805459861u

typedef float v2  __attribute__((ext_vector_type(2)));   // one table entry (8B)
typedef float v4f __attribute__((ext_vector_type(4)));   // 16B output chunk

// int(16 * (32^(1/15))^i) for i in 0..15, replicated exactly from the reference
__constant__ float c_res[16] = {16.f,20.f,25.f,32.f,40.f,50.f,64.f,80.f,
                                101.f,128.f,161.f,203.f,256.f,322.f,406.f,512.f};
// phase order: alternate coarse/fine so the instantaneous table working set is
// (small coarse + one 4MB fine) per XCD-L2, even with modest block drift
__constant__ int c_perm[16] = {0,15,1,14,2,13,3,12,4,11,5,10,6,9,7,8};

// round-0 gather core (8x 8B gathers, no pairing): the paired-16B variant
// regressed (427 vs 354 us) — consistent with a per-lane address-slot limit
// where 16B gathers / exec-masked loads don't reduce cost and add VALU.
__device__ __forceinline__ v2 enc_point_level(float x0, float x1, float x2,
                                              const float* __restrict__ tables,
                                              int level, float res) {
    float sx = x0*res, sy = x1*res, sz = x2*res;
    int ix = (int)sx, iy = (int)sy, iz = (int)sz;   // trunc == floor for x>=0
    float fx = sx - (float)ix, fy = sy - (float)iy, fz = sz - (float)iz;
    uint32_t hx0 = (uint32_t)ix,       hx1 = hx0 + 1u;
    uint32_t hy0 = (uint32_t)iy * PI1, hy1 = hy0 + PI1;
    uint32_t hz0 = (uint32_t)iz * PI2, hz1 = hz0 + PI2;
    const v2* __restrict__ tab = (const v2*)tables + (size_t)level * HASHMAP;
    uint32_t e0 = hy0 ^ hz0, e1 = hy1 ^ hz0, e2 = hy0 ^ hz1, e3 = hy1 ^ hz1;
    uint32_t i0 = (hx0 ^ e0) & HASH_MASK;  // (0,0,0)
    uint32_t i1 = (hx1 ^ e0) & HASH_MASK;  // (1,0,0)
    uint32_t i2 = (hx0 ^ e1) & HASH_MASK;  // (0,1,0)
    uint32_t i3 = (hx1 ^ e1) & HASH_MASK;  // (1,1,0)
    uint32_t i4 = (hx0 ^ e2) & HASH_MASK;  // (0,0,1)
    uint32_t i5 = (hx1 ^ e2) & HASH_MASK;  // (1,0,1)
    uint32_t i6 = (hx0 ^ e3) & HASH_MASK;  // (0,1,1)
    uint32_t i7 = (hx1 ^ e3) & HASH_MASK;  // (1,1,1)
    v2 f0 = tab[i0], f1 = tab[i1], f2 = tab[i2], f3 = tab[i3];
    v2 f4 = tab[i4], f5 = tab[i5], f6 = tab[i6], f7 = tab[i7];
    float wx1 = fx, wx0 = 1.f - fx;
    float wy1 = fy, wy0 = 1.f - fy;
    float wz1 = fz, wz0 = 1.f - fz;
    float w00 = wy0*wz0, w10 = wy1*wz0, w01 = wy0*wz1, w11 = wy1*wz1;
    float c0 = wx0*w00, c1 = wx1*w00, c2 = wx0*w10, c3 = wx1*w10;
    float c4 = wx0*w01, c5 = wx1*w01, c6 = wx0*w11, c7 = wx1*w11;
    v2 r;
    r.x = c0*f0.x + c1*f1.x + c2*f2.x + c3*f3.x + c4*f4.x + c5*f5.x + c6*f6.x + c7*f7.x;
    r.y = c0*f0.y + c1*f1.y + c2*f2.y + c3*f3.y + c4*f4.y + c5*f5.y + c6*f6.y + c7*f7.y;
    return r;
}

// Single-pass persistent kernel. Thread = point; block = 256 points; 16-level
// sweep per chunk in perm order. x is loaded ONCE per point (was 16x), the
// 256MB workspace round-trip and the transpose kernel are gone. Grid = 1024
// blocks = exact 4-blocks/CU residency (34.8KB LDS each), so all blocks start
// together and sweep levels in near-lockstep -> each level's table stays
// per-XCD-L2-resident, like the phased two-pass version.
__global__ __launch_bounds__(256) void hash_enc_all(const float* __restrict__ x,
                                                    const float* __restrict__ tables,
                                                    v4f* __restrict__ out) {
    // [256 points][16 levels] v2, row stride 17 (b64 writes land 4/bankpair =
    // conflict-free floor; paired b64 reads likewise)
    __shared__ v2 tile[256][17];
    int t = threadIdx.x;
    for (int c = 0; c < 4; ++c) {
        int p0 = ((c << 10) | blockIdx.x) << 8;
        int p  = p0 + t;
        float x0 = x[3*p+0], x1 = x[3*p+1], x2 = x[3*p+2];
        #pragma unroll
        for (int l = 0; l < 16; ++l) {
            int lev = c_perm[l];
            v2 r = enc_point_level(x0, x1, x2, tables, lev, c_res[lev]);
            tile[t][lev] = r;
            // pace the block's 4 waves level-by-level (keeps the whole device
            // near one table). Drain cost hides under the CU's other 3
            // independent blocks.
            __syncthreads();
        }
        // tile holds the final (point, 32 floats) rows: write coalesced 16B NT
        #pragma unroll
        for (int k = 0; k < 8; ++k) {
            int j  = (k << 8) | t;          // v4f index within block's output
            int pl = j >> 3, ch = j & 7;
            v2 lo = tile[pl][2*ch];
            v2 hi = tile[pl][2*ch+1];
            v4f v = {lo.x, lo.y, hi.x, hi.y};
            __builtin_nontemporal_store(v, out + ((size_t)p0 << 3) + j);
        }
        __syncthreads();                    // tile reuse across chunks
    }
}

extern "C" void kernel_launch(void* const* d_in, const int* in_sizes, int n_in,
                              void* d_out, int out_size, void* d_ws, size_t ws_size,
                              hipStream_t stream) {
    const float* x      = (const float*)d_in[0];
    const float* tables = (const float*)d_in[1];
    hash_enc_all<<<dim3(1024), dim3(256), 0, stream>>>(x, tables, (v4f*)d_out);
}

// Round 3
// 548.152 us; speedup vs baseline: 1.6897x; 1.4632x over previous
//
#include <hip/hip_runtime.h>
#include <stdint.h>

#define N_POINTS   1048576
#define N_LEVELS   16
#define HASHMAP    524288u        // 1<<19
#define HASH_MASK  (HASHMAP - 1u)
#define PI1        2654435761u
#define PI2        805459861u

typedef float v2  __attribute__((ext_vector_type(2)));   // one table entry (8B)
typedef float v4f __attribute__((ext_vector_type(4)));   // 16B chunk

// int(16 * (32^(1/15))^i) for i in 0..15, replicated exactly from the reference
__constant__ float c_res[16] = {16.f,20.f,25.f,32.f,40.f,50.f,64.f,80.f,
                                101.f,128.f,161.f,203.f,256.f,322.f,406.f,512.f};
// phase order: alternate coarse/fine so adjacent-in-time levels' tables fit L2
__constant__ int c_perm[16] = {0,15,1,14,2,13,3,12,4,11,5,10,6,9,7,8};

// Round-0 gather core: 8x 8B gathers. (16B pairing regressed — costs 2 slots;
// __syncthreads-paced fusion regressed — L2 thrash. Dispatch-order phasing +
// 8B gathers is the verified-best structure.)
__device__ __forceinline__ v2 enc_point_level(float x0, float x1, float x2,
                                              const float* __restrict__ tables,
                                              int level, float res) {
    float sx = x0*res, sy = x1*res, sz = x2*res;
    int ix = (int)sx, iy = (int)sy, iz = (int)sz;   // trunc == floor for x>=0
    float fx = sx - (float)ix, fy = sy - (float)iy, fz = sz - (float)iz;
    uint32_t hx0 = (uint32_t)ix,       hx1 = hx0 + 1u;
    uint32_t hy0 = (uint32_t)iy * PI1, hy1 = hy0 + PI1;
    uint32_t hz0 = (uint32_t)iz * PI2, hz1 = hz0 + PI2;
    const v2* __restrict__ tab = (const v2*)tables + (size_t)level * HASHMAP;
    uint32_t e0 = hy0 ^ hz0, e1 = hy1 ^ hz0, e2 = hy0 ^ hz1, e3 = hy1 ^ hz1;
    uint32_t i0 = (hx0 ^ e0) & HASH_MASK;  // (0,0,0)
    uint32_t i1 = (hx1 ^ e0) & HASH_MASK;  // (1,0,0)
    uint32_t i2 = (hx0 ^ e1) & HASH_MASK;  // (0,1,0)
    uint32_t i3 = (hx1 ^ e1) & HASH_MASK;  // (1,1,0)
    uint32_t i4 = (hx0 ^ e2) & HASH_MASK;  // (0,0,1)
    uint32_t i5 = (hx1 ^ e2) & HASH_MASK;  // (1,0,1)
    uint32_t i6 = (hx0 ^ e3) & HASH_MASK;  // (0,1,1)
    uint32_t i7 = (hx1 ^ e3) & HASH_MASK;  // (1,1,1)
    v2 f0 = tab[i0], f1 = tab[i1], f2 = tab[i2], f3 = tab[i3];
    v2 f4 = tab[i4], f5 = tab[i5], f6 = tab[i6], f7 = tab[i7];
    float wx1 = fx, wx0 = 1.f - fx;
    float wy1 = fy, wy0 = 1.f - fy;
    float wz1 = fz, wz0 = 1.f - fz;
    float w00 = wy0*wz0, w10 = wy1*wz0, w01 = wy0*wz1, w11 = wy1*wz1;
    float c0 = wx0*w00, c1 = wx1*w00, c2 = wx0*w10, c3 = wx1*w10;
    float c4 = wx0*w01, c5 = wx1*w01, c6 = wx0*w11, c7 = wx1*w11;
    v2 r;
    r.x = c0*f0.x + c1*f1.x + c2*f2.x + c3*f3.x + c4*f4.x + c5*f5.x + c6*f6.x + c7*f7.x;
    r.y = c0*f0.y + c1*f1.y + c2*f2.y + c3*f3.y + c4*f4.y + c5*f5.y + c6*f6.y + c7*f7.y;
    return r;
}

// One-shot: split (N,3) x into SoA xy(v2) + z(float): the phase kernel then
// pays 2 load slots instead of 3 per point-level.
__global__ __launch_bounds__(256) void repack_x(const float* __restrict__ x,
                                                v2* __restrict__ xy,
                                                float* __restrict__ z) {
    int p = blockIdx.x * 256 + threadIdx.x;
    float a = x[3*p], b = x[3*p+1], c = x[3*p+2];
    xy[p] = (v2){a, b};
    z[p] = c;
}

// Pass 1 (phased, split-x): blockIdx level-major -> whole device sweeps one
// level at a time -> that level's table is per-XCD-L2-resident.
__global__ __launch_bounds__(256) void hash_enc_phase_s(const v2* __restrict__ xy,
                                                        const float* __restrict__ z,
                                                        const float* __restrict__ tables,
                                                        v2* __restrict__ ws) {
    int level = c_perm[blockIdx.x >> 12];           // 4096 blocks per level
    int p = ((blockIdx.x & 4095) << 8) | threadIdx.x;
    v2 q = xy[p];
    float zz = z[p];
    v2 r = enc_point_level(q.x, q.y, zz, tables, level, c_res[level]);
    __builtin_nontemporal_store(r, ws + (size_t)level * N_POINTS + p);
}

// Pass 1 fallback (no repack region): original round-0 form, 3 scalar x loads.
__global__ __launch_bounds__(256) void hash_enc_phase(const float* __restrict__ x,
                                                      const float* __restrict__ tables,
                                                      v2* __restrict__ ws) {
    int level = c_perm[blockIdx.x >> 12];
    int p = ((blockIdx.x & 4095) << 8) | threadIdx.x;
    v2 r = enc_point_level(x[3*p], x[3*p+1], x[3*p+2], tables, level, c_res[level]);
    __builtin_nontemporal_store(r, ws + (size_t)level * N_POINTS + p);
}

// Pass 2: (L,N,2) -> (N,32f). Per-lane row assembly (16 coalesced NT v2
// loads), then re-coalesce stores through a v4f-granular LDS tile.
// Old version moved floats scalar-by-scalar (96 mem-pipe instrs/point ->
// ~156us of pure issue); this is 40 instrs/point.
// Swizzle col=(c+((p>>3)&7))&7 on a [256][9] v4f tile: write phase -- 8 lanes
// sharing (lane&7)-th bank-start get distinct columns -> b128 floor; read
// phase -- key is wave-uniform per instr, groups of 8 lanes span distinct
// starts -> b128 floor. Verified by arithmetic, check SQ_LDS_BANK_CONFLICT=0.
__global__ __launch_bounds__(256) void untranspose2(const v2* __restrict__ ws,
                                                    v4f* __restrict__ out) {
    __shared__ v4f tile[256][9];
    int t = threadIdx.x;
    int p0 = blockIdx.x << 8;
    v2 r[16];
    #pragma unroll
    for (int l = 0; l < 16; ++l)
        r[l] = __builtin_nontemporal_load(ws + (size_t)l * N_POINTS + p0 + t);
    int keyw = (t >> 3) & 7;
    #pragma unroll
    for (int c = 0; c < 8; ++c) {
        v4f v = {r[2*c].x, r[2*c].y, r[2*c+1].x, r[2*c+1].y};
        tile[t][(c + keyw) & 7] = v;                 // ds_write_b128
    }
    __syncthreads();
    #pragma unroll
    for (int k = 0; k < 8; ++k) {
        int j  = (k << 8) | t;                       // v4f index in block output
        int pl = j >> 3, c = j & 7;
        int key = (pl >> 3) & 7;
        v4f v = tile[pl][(c + key) & 7];             // ds_read_b128
        __builtin_nontemporal_store(v, out + ((size_t)p0 << 3) + j);
    }
}

// Zero-workspace fallback: fused, correct, slow (L2 thrash).
__global__ __launch_bounds__(256) void hash_enc_fused(const float* __restrict__ x,
                                                      const float* __restrict__ tables,
                                                      v2* __restrict__ out) {
    int tid = blockIdx.x * 256 + threadIdx.x;       // 16M threads
    int level = tid & 15;
    int p = tid >> 4;
    v2 r = enc_point_level(x[3*p], x[3*p+1], x[3*p+2], tables, level, c_res[level]);
    out[tid] = r;
}

extern "C" void kernel_launch(void* const* d_in, const int* in_sizes, int n_in,
                              void* d_out, int out_size, void* d_ws, size_t ws_size,
                              hipStream_t stream) {
    const float* x      = (const float*)d_in[0];
    const float* tables = (const float*)d_in[1];
    size_t need_lv    = (size_t)N_LEVELS * N_POINTS * sizeof(v2);          // 128 MB
    size_t need_split = need_lv + (size_t)N_POINTS * (sizeof(v2) + 4);     // +12 MB
    if (ws_size >= need_split) {
        v2*    wsv = (v2*)d_ws;
        v2*    xy  = wsv + (size_t)N_LEVELS * N_POINTS;
        float* z   = (float*)(xy + N_POINTS);
        repack_x<<<dim3(4096), dim3(256), 0, stream>>>(x, xy, z);
        hash_enc_phase_s<<<dim3(65536), dim3(256), 0, stream>>>(xy, z, tables, wsv);
        untranspose2<<<dim3(4096), dim3(256), 0, stream>>>(wsv, (v4f*)d_out);
    } else if (ws_size >= need_lv) {
        hash_enc_phase<<<dim3(65536), dim3(256), 0, stream>>>(x, tables, (v2*)d_ws);
        untranspose2<<<dim3(4096), dim3(256), 0, stream>>>((const v2*)d_ws, (v4f*)d_out);
    } else {
        hash_enc_fused<<<dim3(65536), dim3(256), 0, stream>>>(x, tables, (v2*)d_out);
    }
}